// Round 6
// baseline (582.494 us; speedup 1.0000x reference)
//
#include <hip/hip_runtime.h>
#include <math.h>

#define TT 10
#define BB 32
#define CIN 3
#define COUT 64
#define HH 64
#define WW 64
#define HW (HH*WW)           // 4096
#define DECAY 0.2f
#define INH 1.625f

__device__ __forceinline__ unsigned int enc_f(float f) {
    unsigned int u = __float_as_uint(f);
    return (u & 0x80000000u) ? ~u : (u | 0x80000000u);
}
__device__ __forceinline__ float dec_f(unsigned int u) {
    u = (u & 0x80000000u) ? (u & 0x7FFFFFFFu) : ~u;
    return __uint_as_float(u);
}

// ---------------------------------------------------------------------------
// Pass 1: conv for the threshold max + coalesced zero-fill of the output.
// ORDER MATTERS: the zero-fill stores are issued AFTER the staging barrier
// so they drain underneath the conv VALU work (the pre-barrier placement in
// r5 forced s_waitcnt vmcnt(0) BEFORE the conv -> fill fully serialized).
// Same FMA ordering as pass 2 -> bitwise-identical i values.
// lane = channel (W[27] in VGPRs), wave = row within a 4-row group.
// Plain __launch_bounds__(256): no min-occupancy arg (r2-r4 spill lesson).
// ---------------------------------------------------------------------------
__global__ __launch_bounds__(256) void thr_kernel(
    const float* __restrict__ x,        // (T,B,3,64,64)
    const float* __restrict__ Wt,       // (64,3,3,3)
    unsigned int* __restrict__ thr_raw, // (T,64) pre-zeroed
    float* __restrict__ out)            // (T,B,64,64,64) — zero-filled here
{
    __shared__ float sx[CIN][6][68];    // row stride 68 -> 16B-aligned rows
    __shared__ float wmax[4][COUT];

    const int tid  = threadIdx.x;
    const int lane = tid & 63;          // channel
    const int wave = tid >> 6;          // row within 4-row group
    const int h0   = blockIdx.x * 4;
    const int b    = blockIdx.y;
    const int t    = blockIdx.z;

    float w[27];
    #pragma unroll
    for (int k = 0; k < 27; k++) w[k] = Wt[lane * 27 + k];

    // stage x tile (3 x 6 x 66 used cols), coalesced, zero-padded
    const float* xb = x + ((size_t)t * BB + b) * (CIN * HW);
    for (int l = tid; l < CIN * 6 * 66; l += 256) {
        int ci  = l / 396;
        int r   = (l % 396) / 66;
        int col = l % 66;
        int gh = h0 + r - 1;
        int gw = col - 1;
        float v = 0.f;
        if (gh >= 0 && gh < HH && gw >= 0 && gw < WW)
            v = xb[ci * HW + gh * WW + gw];
        sx[ci][r][col] = v;
    }
    __syncthreads();   // only LDS staging waits here (fill not yet issued)

    // coalesced zero-fill of out[t][b][:][h0:h0+4][:] (64 KB / block),
    // issued NOW so the stores drain under the conv below; the next
    // barrier (before wmax reduce) is what finally waits on them.
    {
        float* ob = out + (((size_t)t * BB + b) * COUT) * HW;
        #pragma unroll
        for (int g = 0; g < 16; g++) {
            int l   = g * 256 + tid;          // 0..4095 float4s
            int row = l >> 4;                 // 0..255 = (c<<2)|hr
            int q   = l & 15;                 // float4 within row
            int c   = row >> 2;
            int hr  = row & 3;
            *(float4*)(ob + (size_t)c * HW + (h0 + hr) * WW + q * 4) =
                make_float4(0.f, 0.f, 0.f, 0.f);
        }
    }

    float mx = -INFINITY;

    for (int cc = 0; cc < 16; cc++) {          // 4-pixel chunks along the row
        float acc0 = 0.f, acc1 = 0.f, acc2 = 0.f, acc3 = 0.f;
        #pragma unroll
        for (int ci = 0; ci < CIN; ci++)
            #pragma unroll
            for (int kh = 0; kh < 3; kh++) {
                // wave-uniform LDS reads: broadcast, conflict-free
                const float* rp = &sx[ci][wave + kh][cc * 4];
                float4 q = *(const float4*)rp;
                float2 r2 = *(const float2*)(rp + 4);
                float x0 = q.x, x1 = q.y, x2 = q.z, x3 = q.w;
                float x4 = r2.x, x5 = r2.y;
                const float w0 = w[ci * 9 + kh * 3 + 0];
                const float w1 = w[ci * 9 + kh * 3 + 1];
                const float w2 = w[ci * 9 + kh * 3 + 2];
                acc0 = fmaf(w0, x0, acc0); acc0 = fmaf(w1, x1, acc0); acc0 = fmaf(w2, x2, acc0);
                acc1 = fmaf(w0, x1, acc1); acc1 = fmaf(w1, x2, acc1); acc1 = fmaf(w2, x3, acc1);
                acc2 = fmaf(w0, x2, acc2); acc2 = fmaf(w1, x3, acc2); acc2 = fmaf(w2, x4, acc2);
                acc3 = fmaf(w0, x3, acc3); acc3 = fmaf(w1, x4, acc3); acc3 = fmaf(w2, x5, acc3);
            }
        mx = fmaxf(mx, fmaxf(fmaxf(acc0, acc1), fmaxf(acc2, acc3)));
    }

    wmax[wave][lane] = mx;
    __syncthreads();   // drains the zero-fill too (hidden under conv above)
    if (wave == 0) {
        float m = fmaxf(fmaxf(wmax[0][lane], wmax[1][lane]),
                        fmaxf(wmax[2][lane], wmax[3][lane]));
        atomicMax(&thr_raw[t * COUT + lane], enc_f(m));
    }
}

// ---------------------------------------------------------------------------
// Pass 2: fused conv + LIF, sparse-store-only output, row-register conv.
// Per (ci,kh) the wave's full 18-float sx row is loaded ONCE (4xb128+1xb64,
// aligned: row stride 272B, p0*4 multiple of 64) into registers and 16
// static accumulators are fed from it: LDS ops 72 -> 45 per wave*t and 16
// independent FMA chains for ILP. Per-accumulator FMA order is IDENTICAL
// to before (w0*f[j], w1*f[j+1], w2*f[j+2] per (ci,kh) in same order) ->
// bit-identical i. out pre-zeroed by thr_kernel; only sparse winner stores.
// Plain __launch_bounds__(256). Grid = B*H = 2048 x 256.
// ---------------------------------------------------------------------------
__global__ __launch_bounds__(256) void fused_kernel(
    const float* __restrict__ x,              // (T,B,3,64,64)
    const float* __restrict__ Wt,             // (64,3,3,3)
    const unsigned int* __restrict__ thr_raw, // (T,64)
    float* __restrict__ out)                  // (T,B,64,64,64) pre-zeroed
{
    __shared__ float sx[5][CIN][3][68];       // 12,240 B; rows 16B-aligned

    const int tid  = threadIdx.x;
    const int lane = tid & 63;                            // channel
    const int wave = tid >> 6;
    const int p0   = __builtin_amdgcn_readfirstlane(wave * 16);
    const int b    = blockIdx.x >> 6;
    const int h    = blockIdx.x & 63;

    float w[27];
    #pragma unroll
    for (int k = 0; k < 27; k++) w[k] = Wt[lane * 27 + k];

    const float* xb0 = x + (size_t)b * (CIN * HW);        // t=0 base, this b

#define STAGE5(T0) {                                                          \
        for (int l = tid; l < 5 * 594; l += 256) {                            \
            int t   = l / 594;                                                \
            int r0  = l - t * 594;                                            \
            int ci  = r0 / 198;                                               \
            int r1  = r0 - ci * 198;                                          \
            int r   = r1 / 66;                                                \
            int col = r1 - r * 66;                                            \
            int gh = h + r - 1;                                               \
            int gw = col - 1;                                                 \
            float v = 0.f;                                                    \
            if (gh >= 0 && gh < HH && gw >= 0 && gw < WW)                     \
                v = xb0[(size_t)((T0) + t) * ((size_t)BB * CIN * HW)          \
                        + ci * HW + gh * WW + gw];                            \
            sx[t][ci][r][col] = v;                                            \
        }                                                                     \
    }

    STAGE5(0);

    float mem[16];
    #pragma unroll
    for (int j = 0; j < 16; j++) mem[j] = 0.f;

    __syncthreads();   // first 5 t staged

    #pragma unroll 1
    for (int t = 0; t < TT; t++) {
        if (t == 5) {               // restage second half (only 2 barriers)
            __syncthreads();
            STAGE5(5);
            __syncthreads();
        }
        const int slot = (t < 5) ? t : t - 5;

        // per-lane threshold word loaded early (latency hides under conv)
        unsigned int tru = thr_raw[t * COUT + lane];

        // ---- conv: 16 static accumulators, row-register operand reuse ----
        float acc[16];
        #pragma unroll
        for (int j = 0; j < 16; j++) acc[j] = 0.f;

        #pragma unroll
        for (int ci = 0; ci < CIN; ci++)
            #pragma unroll
            for (int kh = 0; kh < 3; kh++) {
                const float* rp = &sx[slot][ci][kh][p0];  // 16B-aligned
                float4 q0 = *(const float4*)(rp + 0);
                float4 q1 = *(const float4*)(rp + 4);
                float4 q2 = *(const float4*)(rp + 8);
                float4 q3 = *(const float4*)(rp + 12);
                float2 q4 = *(const float2*)(rp + 16);
                float f[18] = { q0.x, q0.y, q0.z, q0.w,
                                q1.x, q1.y, q1.z, q1.w,
                                q2.x, q2.y, q2.z, q2.w,
                                q3.x, q3.y, q3.z, q3.w,
                                q4.x, q4.y };
                const float w0 = w[ci * 9 + kh * 3 + 0];
                const float w1 = w[ci * 9 + kh * 3 + 1];
                const float w2 = w[ci * 9 + kh * 3 + 2];
                #pragma unroll
                for (int j = 0; j < 16; j++) {
                    acc[j] = fmaf(w0, f[j],     acc[j]);
                    acc[j] = fmaf(w1, f[j + 1], acc[j]);
                    acc[j] = fmaf(w2, f[j + 2], acc[j]);
                }
            }

        // per-lane (= per-channel) threshold constants
        float thr   = dec_f(tru) + 1e-4f;
        float sinv  = 8.0f / thr;
        float s04   = 0.4f * thr;
        float sinh_ = INH * thr;

        int fmask = 0;     // bit j: this lane's channel fired at pixel p0+j

        #pragma unroll
        for (int j = 0; j < 16; j++) {
            float cur = fmaxf(acc[j], 0.f);
            float z   = (cur - s04) * sinv;
            float sig = 1.0f / (1.0f + expf(-z));
            float m   = mem[j] * DECAY + thr * sig;
            int   sp  = m > thr;
            float score = sp ? m : 0.f;

            unsigned long long blt = __ballot(sp);
            int fr = 0, sp_any = 0;
            if (blt) {   // wave-uniform; rare
                float bs = score;
                int   bc = lane;
                #pragma unroll
                for (int off = 32; off > 0; off >>= 1) {
                    float so = __shfl_xor(bs, off, 64);
                    int   co = __shfl_xor(bc, off, 64);
                    if (so > bs || (so == bs && co < bc)) { bs = so; bc = co; }
                }
                int spw = __shfl(sp, bc, 64);   // winner's spike = any_sp
                fr     = (lane == bc) && sp;
                sp_any = spw;
            }
            mem[j] = fr ? 0.f : (m - (sp_any ? sinh_ : 0.f));
            if (fr) fmask |= (1 << j);
        }

        // sparse winner stores (rare); out pre-zeroed by thr_kernel; each
        // address written by exactly one thread -> no ordering needed
        if (fmask) {
            float* os = out + (((size_t)t * BB + b) * COUT) * HW + h * WW;
            #pragma unroll
            for (int j = 0; j < 16; j++)
                if (fmask & (1 << j))
                    os[(size_t)lane * HW + p0 + j] = 1.0f;
        }
    }
#undef STAGE5
}

// ---------------------------------------------------------------------------
extern "C" void kernel_launch(void* const* d_in, const int* in_sizes, int n_in,
                              void* d_out, int out_size, void* d_ws, size_t ws_size,
                              hipStream_t stream) {
    const float* x = (const float*)d_in[0];   // (T,B,3,64,64)
    const float* W = (const float*)d_in[1];   // (64,3,3,3)
    float* out     = (float*)d_out;           // (T,B,64,64,64)

    unsigned int* thr = (unsigned int*)d_ws;  // (T,64) — only 2.5 KB of ws used
    hipMemsetAsync(thr, 0, TT * COUT * sizeof(unsigned int), stream);

    thr_kernel<<<dim3(HH / 4, BB, TT), 256, 0, stream>>>(x, W, thr, out);
    fused_kernel<<<dim3(BB * HH), 256, 0, stream>>>(x, W, thr, out);
}

// Round 7
// 527.167 us; speedup vs baseline: 1.1050x; 1.1050x over previous
//
#include <hip/hip_runtime.h>
#include <math.h>

#define TT 10
#define BB 32
#define CIN 3
#define COUT 64
#define HH 64
#define WW 64
#define HW (HH*WW)           // 4096
#define DECAY 0.2f
#define INH 1.625f

__device__ __forceinline__ unsigned int enc_f(float f) {
    unsigned int u = __float_as_uint(f);
    return (u & 0x80000000u) ? ~u : (u | 0x80000000u);
}
__device__ __forceinline__ float dec_f(unsigned int u) {
    u = (u & 0x80000000u) ? (u & 0x7FFFFFFFu) : ~u;
    return __uint_as_float(u);
}

// ---------------------------------------------------------------------------
// Pass 1: conv for the threshold max + coalesced zero-fill of the output
// (fill issued after the staging barrier so it drains under the conv VALU).
// Same FMA ordering as pass 2 -> bitwise-identical i values.
// lane = channel (W[27] in VGPRs), wave = row within a 4-row group.
// Plain __launch_bounds__(256): no min-occupancy arg (r2-r4 spill lesson).
// UNCHANGED from round 6 (so the bench delta attributes to fused_kernel).
// ---------------------------------------------------------------------------
__global__ __launch_bounds__(256) void thr_kernel(
    const float* __restrict__ x,        // (T,B,3,64,64)
    const float* __restrict__ Wt,       // (64,3,3,3)
    unsigned int* __restrict__ thr_raw, // (T,64) pre-zeroed
    float* __restrict__ out)            // (T,B,64,64,64) — zero-filled here
{
    __shared__ float sx[CIN][6][68];    // row stride 68 -> 16B-aligned rows
    __shared__ float wmax[4][COUT];

    const int tid  = threadIdx.x;
    const int lane = tid & 63;          // channel
    const int wave = tid >> 6;          // row within 4-row group
    const int h0   = blockIdx.x * 4;
    const int b    = blockIdx.y;
    const int t    = blockIdx.z;

    float w[27];
    #pragma unroll
    for (int k = 0; k < 27; k++) w[k] = Wt[lane * 27 + k];

    // stage x tile (3 x 6 x 66 used cols), coalesced, zero-padded
    const float* xb = x + ((size_t)t * BB + b) * (CIN * HW);
    for (int l = tid; l < CIN * 6 * 66; l += 256) {
        int ci  = l / 396;
        int r   = (l % 396) / 66;
        int col = l % 66;
        int gh = h0 + r - 1;
        int gw = col - 1;
        float v = 0.f;
        if (gh >= 0 && gh < HH && gw >= 0 && gw < WW)
            v = xb[ci * HW + gh * WW + gw];
        sx[ci][r][col] = v;
    }
    __syncthreads();   // only LDS staging waits here (fill not yet issued)

    // coalesced zero-fill of out[t][b][:][h0:h0+4][:] (64 KB / block),
    // drains under the conv; final barrier (before wmax reduce) waits on it.
    {
        float* ob = out + (((size_t)t * BB + b) * COUT) * HW;
        #pragma unroll
        for (int g = 0; g < 16; g++) {
            int l   = g * 256 + tid;          // 0..4095 float4s
            int row = l >> 4;                 // 0..255 = (c<<2)|hr
            int q   = l & 15;                 // float4 within row
            int c   = row >> 2;
            int hr  = row & 3;
            *(float4*)(ob + (size_t)c * HW + (h0 + hr) * WW + q * 4) =
                make_float4(0.f, 0.f, 0.f, 0.f);
        }
    }

    float mx = -INFINITY;

    for (int cc = 0; cc < 16; cc++) {          // 4-pixel chunks along the row
        float acc0 = 0.f, acc1 = 0.f, acc2 = 0.f, acc3 = 0.f;
        #pragma unroll
        for (int ci = 0; ci < CIN; ci++)
            #pragma unroll
            for (int kh = 0; kh < 3; kh++) {
                // wave-uniform LDS reads: broadcast, conflict-free
                const float* rp = &sx[ci][wave + kh][cc * 4];
                float4 q = *(const float4*)rp;
                float2 r2 = *(const float2*)(rp + 4);
                float x0 = q.x, x1 = q.y, x2 = q.z, x3 = q.w;
                float x4 = r2.x, x5 = r2.y;
                const float w0 = w[ci * 9 + kh * 3 + 0];
                const float w1 = w[ci * 9 + kh * 3 + 1];
                const float w2 = w[ci * 9 + kh * 3 + 2];
                acc0 = fmaf(w0, x0, acc0); acc0 = fmaf(w1, x1, acc0); acc0 = fmaf(w2, x2, acc0);
                acc1 = fmaf(w0, x1, acc1); acc1 = fmaf(w1, x2, acc1); acc1 = fmaf(w2, x3, acc1);
                acc2 = fmaf(w0, x2, acc2); acc2 = fmaf(w1, x3, acc2); acc2 = fmaf(w2, x4, acc2);
                acc3 = fmaf(w0, x3, acc3); acc3 = fmaf(w1, x4, acc3); acc3 = fmaf(w2, x5, acc3);
            }
        mx = fmaxf(mx, fmaxf(fmaxf(acc0, acc1), fmaxf(acc2, acc3)));
    }

    wmax[wave][lane] = mx;
    __syncthreads();   // drains the zero-fill too (hidden under conv above)
    if (wave == 0) {
        float m = fmaxf(fmaxf(wmax[0][lane], wmax[1][lane]),
                        fmaxf(wmax[2][lane], wmax[3][lane]));
        atomicMax(&thr_raw[t * COUT + lane], enc_f(m));
    }
}

// ---------------------------------------------------------------------------
// Pass 2: fused conv + LIF, HALF-ROW blocks for occupancy.
// The LIF recurrence is pointwise in (h,w) -> split each row in two:
// grid = B*H*2 = 4096 blocks, each wave owns 8 pixels (mem[8]). Halves
// per-thread register state (VGPR ~120 -> ~85, 6 waves/SIMD) and doubles
// schedulable blocks — attacks r6's measured 20.8% occupancy.
// Conv is the r5 chunked form (4 live accs, conv->LIF interleaved per
// 4-px chunk; r6's f[18] row-register form regressed). FMA order per
// accumulator unchanged -> bit-identical i. out pre-zeroed by thr_kernel;
// only sparse winner stores. x staged 5 t at a time (6.5 KB LDS).
// ---------------------------------------------------------------------------
__global__ __launch_bounds__(256) void fused_kernel(
    const float* __restrict__ x,              // (T,B,3,64,64)
    const float* __restrict__ Wt,             // (64,3,3,3)
    const unsigned int* __restrict__ thr_raw, // (T,64)
    float* __restrict__ out)                  // (T,B,64,64,64) pre-zeroed
{
    __shared__ float sx[5][CIN][3][36];       // 6,480 B; row stride 144B (16B-aligned)

    const int tid  = threadIdx.x;
    const int lane = tid & 63;                            // channel
    const int wave = tid >> 6;
    const int p0   = __builtin_amdgcn_readfirstlane(wave * 8);  // local pixel base
    const int b    = blockIdx.x >> 7;
    const int h    = (blockIdx.x >> 1) & 63;
    const int w0   = (blockIdx.x & 1) << 5;               // half-row start

    float w[27];
    #pragma unroll
    for (int k = 0; k < 27; k++) w[k] = Wt[lane * 27 + k];

    const float* xb0 = x + (size_t)b * (CIN * HW);        // t=0 base, this b

    // sx[t][ci][r][col] holds x[gw = w0 + col - 1] for rows h-1..h+1;
    // cols 0..33 used (halo both sides), 34..35 pad.
#define STAGE5(T0) {                                                          \
        for (int l = tid; l < 5 * 306; l += 256) {                            \
            int t   = l / 306;                                                \
            int r0  = l - t * 306;                                            \
            int ci  = r0 / 102;                                               \
            int r1  = r0 - ci * 102;                                          \
            int r   = r1 / 34;                                                \
            int col = r1 - r * 34;                                            \
            int gh = h + r - 1;                                               \
            int gw = w0 + col - 1;                                            \
            float v = 0.f;                                                    \
            if (gh >= 0 && gh < HH && gw >= 0 && gw < WW)                     \
                v = xb0[(size_t)((T0) + t) * ((size_t)BB * CIN * HW)          \
                        + ci * HW + gh * WW + gw];                            \
            sx[t][ci][r][col] = v;                                            \
        }                                                                     \
    }

    STAGE5(0);

    float mem[8];
    #pragma unroll
    for (int j = 0; j < 8; j++) mem[j] = 0.f;

    __syncthreads();   // first 5 t staged

    #pragma unroll 1
    for (int t = 0; t < TT; t++) {
        if (t == 5) {               // restage second half (only 2 barriers)
            __syncthreads();
            STAGE5(5);
            __syncthreads();
        }
        const int slot = (t < 5) ? t : t - 5;

        // per-lane (= per-channel) threshold constants (L2-resident 2.5 KB)
        float thr   = dec_f(thr_raw[t * COUT + lane]) + 1e-4f;
        float sinv  = 8.0f / thr;
        float s04   = 0.4f * thr;
        float sinh_ = INH * thr;

        int fmask = 0;     // bit j: this lane's channel fired at local pixel p0+j

#define LIF_PX(J, ACC) {                                                    \
        float cur = fmaxf(ACC, 0.f);                                        \
        float z   = (cur - s04) * sinv;                                     \
        float sig = 1.0f / (1.0f + expf(-z));                               \
        float m   = mem[J] * DECAY + thr * sig;                             \
        int   sp  = m > thr;                                                \
        float score = sp ? m : 0.f;                                         \
        unsigned long long blt = __ballot(sp);                              \
        int fr = 0, sp_any = 0;                                             \
        if (blt) {   /* wave-uniform; rare */                               \
            float bs = score;                                               \
            int   bc = lane;                                                \
            _Pragma("unroll")                                               \
            for (int off = 32; off > 0; off >>= 1) {                        \
                float so = __shfl_xor(bs, off, 64);                         \
                int   co = __shfl_xor(bc, off, 64);                         \
                if (so > bs || (so == bs && co < bc)) { bs = so; bc = co; } \
            }                                                               \
            int spw = __shfl(sp, bc, 64);   /* winner's spike = any_sp */   \
            fr     = (lane == bc) && sp;                                    \
            sp_any = spw;                                                   \
        }                                                                   \
        mem[J] = fr ? 0.f : (m - (sp_any ? sinh_ : 0.f));                   \
        if (fr) fmask |= (1 << (J));                                        \
    }

        #pragma unroll
        for (int ch = 0; ch < 2; ch++) {       // 4-pixel chunks of this wave
            const int c0 = p0 + ch * 4;        // chunk start (local pixel)
            float acc0 = 0.f, acc1 = 0.f, acc2 = 0.f, acc3 = 0.f;
            #pragma unroll
            for (int ci = 0; ci < CIN; ci++)
                #pragma unroll
                for (int kh = 0; kh < 3; kh++) {
                    // wave-uniform LDS reads: broadcast, conflict-free;
                    // col c0 holds x[w0+c0-1] -> f[j] = x at kw=-1 of px c0+j
                    const float* rp = &sx[slot][ci][kh][c0];  // 16B-aligned
                    float4 q = *(const float4*)rp;
                    float2 r2 = *(const float2*)(rp + 4);
                    float x0 = q.x, x1 = q.y, x2 = q.z, x3 = q.w;
                    float x4 = r2.x, x5 = r2.y;
                    const float w0_ = w[ci * 9 + kh * 3 + 0];
                    const float w1_ = w[ci * 9 + kh * 3 + 1];
                    const float w2_ = w[ci * 9 + kh * 3 + 2];
                    acc0 = fmaf(w0_, x0, acc0); acc0 = fmaf(w1_, x1, acc0); acc0 = fmaf(w2_, x2, acc0);
                    acc1 = fmaf(w0_, x1, acc1); acc1 = fmaf(w1_, x2, acc1); acc1 = fmaf(w2_, x3, acc1);
                    acc2 = fmaf(w0_, x2, acc2); acc2 = fmaf(w1_, x3, acc2); acc2 = fmaf(w2_, x4, acc2);
                    acc3 = fmaf(w0_, x3, acc3); acc3 = fmaf(w1_, x4, acc3); acc3 = fmaf(w2_, x5, acc3);
                }
            LIF_PX(ch * 4 + 0, acc0);
            LIF_PX(ch * 4 + 1, acc1);
            LIF_PX(ch * 4 + 2, acc2);
            LIF_PX(ch * 4 + 3, acc3);
        }
#undef LIF_PX

        // sparse winner stores (rare); out pre-zeroed by thr_kernel; each
        // address written by exactly one thread -> no ordering needed
        if (fmask) {
            float* os = out + (((size_t)t * BB + b) * COUT) * HW + h * WW + w0;
            #pragma unroll
            for (int j = 0; j < 8; j++)
                if (fmask & (1 << j))
                    os[(size_t)lane * HW + p0 + j] = 1.0f;
        }
    }
#undef STAGE5
}

// ---------------------------------------------------------------------------
extern "C" void kernel_launch(void* const* d_in, const int* in_sizes, int n_in,
                              void* d_out, int out_size, void* d_ws, size_t ws_size,
                              hipStream_t stream) {
    const float* x = (const float*)d_in[0];   // (T,B,3,64,64)
    const float* W = (const float*)d_in[1];   // (64,3,3,3)
    float* out     = (float*)d_out;           // (T,B,64,64,64)

    unsigned int* thr = (unsigned int*)d_ws;  // (T,64) — only 2.5 KB of ws used
    hipMemsetAsync(thr, 0, TT * COUT * sizeof(unsigned int), stream);

    thr_kernel<<<dim3(HH / 4, BB, TT), 256, 0, stream>>>(x, W, thr, out);
    fused_kernel<<<dim3(BB * HH * 2), 256, 0, stream>>>(x, W, thr, out);
}

// Round 8
// 518.863 us; speedup vs baseline: 1.1226x; 1.0160x over previous
//
#include <hip/hip_runtime.h>
#include <math.h>

#define TT 10
#define BB 32
#define CIN 3
#define COUT 64
#define HH 64
#define WW 64
#define HW (HH*WW)           // 4096
#define DECAY 0.2f
#define INH 1.625f

__device__ __forceinline__ unsigned int enc_f(float f) {
    unsigned int u = __float_as_uint(f);
    return (u & 0x80000000u) ? ~u : (u | 0x80000000u);
}
__device__ __forceinline__ float dec_f(unsigned int u) {
    u = (u & 0x80000000u) ? (u & 0x7FFFFFFFu) : ~u;
    return __uint_as_float(u);
}

// ---------------------------------------------------------------------------
// Pass 1: conv for the threshold max + zero-fill of the output, INTERLEAVED:
// one 16B fill store per conv chunk so each store's drain hides under ~108
// FMAs (r7 burst-issued all 16 stores first -> store-queue stall before the
// conv even started). Same FMA ordering as pass 2 -> bitwise-identical i.
// lane = channel (W[27] in VGPRs), wave = row within a 4-row group.
// Plain __launch_bounds__(256): no min-occupancy arg (r2-r4 spill lesson).
// ---------------------------------------------------------------------------
__global__ __launch_bounds__(256) void thr_kernel(
    const float* __restrict__ x,        // (T,B,3,64,64)
    const float* __restrict__ Wt,       // (64,3,3,3)
    unsigned int* __restrict__ thr_raw, // (T,64) pre-zeroed
    float* __restrict__ out)            // (T,B,64,64,64) — zero-filled here
{
    __shared__ float sx[CIN][6][68];    // row stride 68 -> 16B-aligned rows
    __shared__ float wmax[4][COUT];

    const int tid  = threadIdx.x;
    const int lane = tid & 63;          // channel
    const int wave = tid >> 6;          // row within 4-row group
    const int h0   = blockIdx.x * 4;
    const int b    = blockIdx.y;
    const int t    = blockIdx.z;

    float w[27];
    #pragma unroll
    for (int k = 0; k < 27; k++) w[k] = Wt[lane * 27 + k];

    // stage x tile (3 x 6 x 66 used cols), coalesced, zero-padded
    const float* xb = x + ((size_t)t * BB + b) * (CIN * HW);
    for (int l = tid; l < CIN * 6 * 66; l += 256) {
        int ci  = l / 396;
        int r   = (l % 396) / 66;
        int col = l % 66;
        int gh = h0 + r - 1;
        int gw = col - 1;
        float v = 0.f;
        if (gh >= 0 && gh < HH && gw >= 0 && gw < WW)
            v = xb[ci * HW + gh * WW + gw];
        sx[ci][r][col] = v;
    }
    __syncthreads();   // only LDS staging waits here

    float* ob = out + (((size_t)t * BB + b) * COUT) * HW;
    float mx = -INFINITY;

    for (int cc = 0; cc < 16; cc++) {          // 4-pixel chunks along the row
        // one fill store per chunk: 64KB/block spread across the whole conv
        {
            int l   = cc * 256 + tid;         // 0..4095 float4s
            int row = l >> 4;                 // 0..255 = (c<<2)|hr
            int q   = l & 15;                 // float4 within row
            int c   = row >> 2;
            int hr  = row & 3;
            *(float4*)(ob + (size_t)c * HW + (h0 + hr) * WW + q * 4) =
                make_float4(0.f, 0.f, 0.f, 0.f);
        }
        float acc0 = 0.f, acc1 = 0.f, acc2 = 0.f, acc3 = 0.f;
        #pragma unroll
        for (int ci = 0; ci < CIN; ci++)
            #pragma unroll
            for (int kh = 0; kh < 3; kh++) {
                // wave-uniform LDS reads: broadcast, conflict-free
                const float* rp = &sx[ci][wave + kh][cc * 4];
                float4 q = *(const float4*)rp;
                float2 r2 = *(const float2*)(rp + 4);
                float x0 = q.x, x1 = q.y, x2 = q.z, x3 = q.w;
                float x4 = r2.x, x5 = r2.y;
                const float w0 = w[ci * 9 + kh * 3 + 0];
                const float w1 = w[ci * 9 + kh * 3 + 1];
                const float w2 = w[ci * 9 + kh * 3 + 2];
                acc0 = fmaf(w0, x0, acc0); acc0 = fmaf(w1, x1, acc0); acc0 = fmaf(w2, x2, acc0);
                acc1 = fmaf(w0, x1, acc1); acc1 = fmaf(w1, x2, acc1); acc1 = fmaf(w2, x3, acc1);
                acc2 = fmaf(w0, x2, acc2); acc2 = fmaf(w1, x3, acc2); acc2 = fmaf(w2, x4, acc2);
                acc3 = fmaf(w0, x3, acc3); acc3 = fmaf(w1, x4, acc3); acc3 = fmaf(w2, x5, acc3);
            }
        mx = fmaxf(mx, fmaxf(fmaxf(acc0, acc1), fmaxf(acc2, acc3)));
    }

    wmax[wave][lane] = mx;
    __syncthreads();   // drains the interleaved fill too (hidden under conv)
    if (wave == 0) {
        float m = fmaxf(fmaxf(wmax[0][lane], wmax[1][lane]),
                        fmaxf(wmax[2][lane], wmax[3][lane]));
        atomicMax(&thr_raw[t * COUT + lane], enc_f(m));
    }
}

// ---------------------------------------------------------------------------
// Pass 2: fused conv + LIF, QUARTER-ROW blocks for occupancy.
// The LIF recurrence is pointwise in (h,w) -> grid = B*H*4 = 8192 blocks,
// each wave owns 4 pixels (mem[4]). ~60 VGPR -> 8 waves/SIMD, and each
// wave's serial per-t chain halves again (r6->r7 proved this lever: the
// half-row split took fused 218 -> ~158us). Conv FMA order per accumulator
// unchanged -> bit-identical i. out pre-zeroed by thr_kernel; only sparse
// winner stores. x staged 5 t at a time (4.3 KB LDS).
// ---------------------------------------------------------------------------
__global__ __launch_bounds__(256) void fused_kernel(
    const float* __restrict__ x,              // (T,B,3,64,64)
    const float* __restrict__ Wt,             // (64,3,3,3)
    const unsigned int* __restrict__ thr_raw, // (T,64)
    float* __restrict__ out)                  // (T,B,64,64,64) pre-zeroed
{
    __shared__ float sx[5][CIN][3][24];       // 4,320 B; row stride 96B (16B-aligned)

    const int tid  = threadIdx.x;
    const int lane = tid & 63;                            // channel
    const int wave = tid >> 6;
    const int p0   = __builtin_amdgcn_readfirstlane(wave * 4);  // local pixel base
    const int b    = blockIdx.x >> 8;
    const int h    = (blockIdx.x >> 2) & 63;
    const int w0   = (blockIdx.x & 3) << 4;               // quarter-row start

    float w[27];
    #pragma unroll
    for (int k = 0; k < 27; k++) w[k] = Wt[lane * 27 + k];

    const float* xb0 = x + (size_t)b * (CIN * HW);        // t=0 base, this b

    // sx[t][ci][r][col] holds x[gw = w0 + col - 1] for rows h-1..h+1;
    // cols 0..17 used (halo both sides), 18..23 pad.
#define STAGE5(T0) {                                                          \
        for (int l = tid; l < 5 * 162; l += 256) {                            \
            int t   = l / 162;                                                \
            int r0  = l - t * 162;                                            \
            int ci  = r0 / 54;                                                \
            int r1  = r0 - ci * 54;                                           \
            int r   = r1 / 18;                                                \
            int col = r1 - r * 18;                                            \
            int gh = h + r - 1;                                               \
            int gw = w0 + col - 1;                                            \
            float v = 0.f;                                                    \
            if (gh >= 0 && gh < HH && gw >= 0 && gw < WW)                     \
                v = xb0[(size_t)((T0) + t) * ((size_t)BB * CIN * HW)          \
                        + ci * HW + gh * WW + gw];                            \
            sx[t][ci][r][col] = v;                                            \
        }                                                                     \
    }

    STAGE5(0);

    float mem[4];
    #pragma unroll
    for (int j = 0; j < 4; j++) mem[j] = 0.f;

    __syncthreads();   // first 5 t staged

    #pragma unroll 1
    for (int t = 0; t < TT; t++) {
        if (t == 5) {               // restage second half (only 2 barriers)
            __syncthreads();
            STAGE5(5);
            __syncthreads();
        }
        const int slot = (t < 5) ? t : t - 5;

        // per-lane (= per-channel) threshold constants (L2-resident 2.5 KB)
        float thr   = dec_f(thr_raw[t * COUT + lane]) + 1e-4f;
        float sinv  = 8.0f / thr;
        float s04   = 0.4f * thr;
        float sinh_ = INH * thr;

        int fmask = 0;     // bit j: this lane's channel fired at local pixel p0+j

        // ---- conv: 4 accumulators from one row-register load per (ci,kh) --
        float acc0 = 0.f, acc1 = 0.f, acc2 = 0.f, acc3 = 0.f;
        #pragma unroll
        for (int ci = 0; ci < CIN; ci++)
            #pragma unroll
            for (int kh = 0; kh < 3; kh++) {
                // wave-uniform LDS reads: broadcast, conflict-free;
                // col p0 holds x[w0+p0-1] -> operand at kw=-1 of pixel p0
                const float* rp = &sx[slot][ci][kh][p0];  // 16B-aligned
                float4 q = *(const float4*)rp;
                float2 r2 = *(const float2*)(rp + 4);
                float x0 = q.x, x1 = q.y, x2 = q.z, x3 = q.w;
                float x4 = r2.x, x5 = r2.y;
                const float w0_ = w[ci * 9 + kh * 3 + 0];
                const float w1_ = w[ci * 9 + kh * 3 + 1];
                const float w2_ = w[ci * 9 + kh * 3 + 2];
                acc0 = fmaf(w0_, x0, acc0); acc0 = fmaf(w1_, x1, acc0); acc0 = fmaf(w2_, x2, acc0);
                acc1 = fmaf(w0_, x1, acc1); acc1 = fmaf(w1_, x2, acc1); acc1 = fmaf(w2_, x3, acc1);
                acc2 = fmaf(w0_, x2, acc2); acc2 = fmaf(w1_, x3, acc2); acc2 = fmaf(w2_, x4, acc2);
                acc3 = fmaf(w0_, x3, acc3); acc3 = fmaf(w1_, x4, acc3); acc3 = fmaf(w2_, x5, acc3);
            }

#define LIF_PX(J, ACC) {                                                    \
        float cur = fmaxf(ACC, 0.f);                                        \
        float z   = (cur - s04) * sinv;                                     \
        float sig = 1.0f / (1.0f + expf(-z));                               \
        float m   = mem[J] * DECAY + thr * sig;                             \
        int   sp  = m > thr;                                                \
        float score = sp ? m : 0.f;                                         \
        unsigned long long blt = __ballot(sp);                              \
        int fr = 0, sp_any = 0;                                             \
        if (blt) {   /* wave-uniform; rare */                               \
            float bs = score;                                               \
            int   bc = lane;                                                \
            _Pragma("unroll")                                               \
            for (int off = 32; off > 0; off >>= 1) {                        \
                float so = __shfl_xor(bs, off, 64);                         \
                int   co = __shfl_xor(bc, off, 64);                         \
                if (so > bs || (so == bs && co < bc)) { bs = so; bc = co; } \
            }                                                               \
            int spw = __shfl(sp, bc, 64);   /* winner's spike = any_sp */   \
            fr     = (lane == bc) && sp;                                    \
            sp_any = spw;                                                   \
        }                                                                   \
        mem[J] = fr ? 0.f : (m - (sp_any ? sinh_ : 0.f));                   \
        if (fr) fmask |= (1 << (J));                                        \
    }

        LIF_PX(0, acc0);
        LIF_PX(1, acc1);
        LIF_PX(2, acc2);
        LIF_PX(3, acc3);
#undef LIF_PX

        // sparse winner stores (rare); out pre-zeroed by thr_kernel; each
        // address written by exactly one thread -> no ordering needed
        if (fmask) {
            float* os = out + (((size_t)t * BB + b) * COUT) * HW + h * WW + w0;
            #pragma unroll
            for (int j = 0; j < 4; j++)
                if (fmask & (1 << j))
                    os[(size_t)lane * HW + p0 + j] = 1.0f;
        }
    }
#undef STAGE5
}

// ---------------------------------------------------------------------------
extern "C" void kernel_launch(void* const* d_in, const int* in_sizes, int n_in,
                              void* d_out, int out_size, void* d_ws, size_t ws_size,
                              hipStream_t stream) {
    const float* x = (const float*)d_in[0];   // (T,B,3,64,64)
    const float* W = (const float*)d_in[1];   // (64,3,3,3)
    float* out     = (float*)d_out;           // (T,B,64,64,64)

    unsigned int* thr = (unsigned int*)d_ws;  // (T,64) — only 2.5 KB of ws used
    hipMemsetAsync(thr, 0, TT * COUT * sizeof(unsigned int), stream);

    thr_kernel<<<dim3(HH / 4, BB, TT), 256, 0, stream>>>(x, W, thr, out);
    fused_kernel<<<dim3(BB * HH * 4), 256, 0, stream>>>(x, W, thr, out);
}